// Round 1
// baseline (147.166 us; speedup 1.0000x reference)
//
#include <hip/hip_runtime.h>
#include <hip/hip_bf16.h>

#define NS 0.2f

// Problem sizes (fixed): B=8, S=1024, D=512, H=8, OD=64

// ---------------------------------------------------------------------------
// aX[row*8+h] = sum_d X[row][d] * W[h][d]     (rows = B*S = 8192)
// block = 256 (4 waves), each wave computes one row's 8 head-dots
// ---------------------------------------------------------------------------
__global__ __launch_bounds__(256) void proj8_kernel(
    const float* __restrict__ X, const float* __restrict__ W,
    float* __restrict__ aX) {
  __shared__ __align__(16) float Wl[8 * 512];
  int t = threadIdx.x;
#pragma unroll
  for (int i = 0; i < 16; i++) Wl[i * 256 + t] = W[i * 256 + t];
  __syncthreads();
  int w = t >> 6, lane = t & 63;
  int row = blockIdx.x * 4 + w;
  const float* x = X + (size_t)row * 512;
  float4 x0 = *(const float4*)(x + lane * 4);
  float4 x1 = *(const float4*)(x + 256 + lane * 4);
  float acc[8];
#pragma unroll
  for (int h = 0; h < 8; h++) {
    const float* wl = Wl + h * 512;
    float4 w0 = *(const float4*)(wl + lane * 4);
    float4 w1 = *(const float4*)(wl + 256 + lane * 4);
    float a = x0.x * w0.x + x0.y * w0.y + x0.z * w0.z + x0.w * w0.w +
              x1.x * w1.x + x1.y * w1.y + x1.z * w1.z + x1.w * w1.w;
#pragma unroll
    for (int off = 32; off > 0; off >>= 1) a += __shfl_xor(a, off);
    acc[h] = a;
  }
  if (lane == 0) {
    float* o = aX + (size_t)row * 8;
    o[0] = acc[0]; o[1] = acc[1]; o[2] = acc[2]; o[3] = acc[3];
    o[4] = acc[4]; o[5] = acc[5]; o[6] = acc[6]; o[7] = acc[7];
  }
}

// ---------------------------------------------------------------------------
// Vproj = V(8192x512) @ WV.T(512x512)  -> C(8192x512), f32 LDS-tiled GEMM
// block 256, tile 64x64, 4x4 acc per thread
// ---------------------------------------------------------------------------
__global__ __launch_bounds__(256) void vproj_gemm(
    const float* __restrict__ A, const float* __restrict__ Wv,
    float* __restrict__ C) {
  __shared__ __align__(16) float As[16][68];
  __shared__ __align__(16) float Bs[16][68];
  int t = threadIdx.x;
  int m0 = blockIdx.x * 64, n0 = blockIdx.y * 64;
  int tx = t & 15, ty = t >> 4;
  int lr = t >> 2, lk = (t & 3) * 4;
  float acc[4][4] = {{0.f}};
  const float* ap = A + (size_t)(m0 + lr) * 512 + lk;
  const float* bp = Wv + (size_t)(n0 + lr) * 512 + lk;
  for (int k0 = 0; k0 < 512; k0 += 16) {
    float4 av = *(const float4*)(ap + k0);
    float4 bv = *(const float4*)(bp + k0);
    __syncthreads();
    As[lk + 0][lr] = av.x; As[lk + 1][lr] = av.y;
    As[lk + 2][lr] = av.z; As[lk + 3][lr] = av.w;
    Bs[lk + 0][lr] = bv.x; Bs[lk + 1][lr] = bv.y;
    Bs[lk + 2][lr] = bv.z; Bs[lk + 3][lr] = bv.w;
    __syncthreads();
#pragma unroll
    for (int kk = 0; kk < 16; kk++) {
      float4 a4 = *(const float4*)&As[kk][ty * 4];
      float4 b4 = *(const float4*)&Bs[kk][tx * 4];
      float aa[4] = {a4.x, a4.y, a4.z, a4.w};
      float bb[4] = {b4.x, b4.y, b4.z, b4.w};
#pragma unroll
      for (int i = 0; i < 4; i++)
#pragma unroll
        for (int j = 0; j < 4; j++) acc[i][j] += aa[i] * bb[j];
    }
  }
#pragma unroll
  for (int i = 0; i < 4; i++) {
    float4 o = {acc[i][0], acc[i][1], acc[i][2], acc[i][3]};
    *(float4*)(C + (size_t)(m0 + ty * 4 + i) * 512 + n0 + tx * 4) = o;
  }
}

// ---------------------------------------------------------------------------
// Per (b,h): bitonic sort of aK column (1024 values) ascending, with index
// ---------------------------------------------------------------------------
__global__ __launch_bounds__(1024) void sort_kernel(
    const float* __restrict__ aK, float* __restrict__ sortedA,
    int* __restrict__ sortedIdx) {
  int bh = blockIdx.x, b = bh >> 3, h = bh & 7;
  __shared__ float key[1024];
  __shared__ int idx[1024];
  int t = threadIdx.x;
  key[t] = aK[(size_t)(b * 1024 + t) * 8 + h];
  idx[t] = t;
  __syncthreads();
  for (int len = 2; len <= 1024; len <<= 1) {
    for (int stride = len >> 1; stride > 0; stride >>= 1) {
      int p = t ^ stride;
      if (p > t) {
        bool up = ((t & len) == 0);
        float k1 = key[t], k2 = key[p];
        if ((k1 > k2) == up) {
          int i1 = idx[t];
          key[t] = k2; key[p] = k1;
          idx[t] = idx[p]; idx[p] = i1;
        }
      }
      __syncthreads();
    }
  }
  sortedA[bh * 1024 + t] = key[t];
  sortedIdx[bh * 1024 + t] = idx[t];
}

// ---------------------------------------------------------------------------
// ix[task] = lower bound: first index in sortedA[bh] with a > -x
// task = b*8192 + q*8 + h
// ---------------------------------------------------------------------------
__global__ __launch_bounds__(256) void ix_kernel(
    const float* __restrict__ aQ, const float* __restrict__ sortedA,
    int* __restrict__ ixArr) {
  int t = blockIdx.x * 256 + threadIdx.x;  // 0..65535
  int h = t & 7, b = t >> 13;
  int bh = b * 8 + h;
  float negx = -aQ[t];
  const float* a = sortedA + bh * 1024;
  int lo = 0, hi = 1024;
  while (lo < hi) {
    int mid = (lo + hi) >> 1;
    if (a[mid] <= negx) lo = mid + 1; else hi = mid;
  }
  ixArr[t] = lo;
}

// ---------------------------------------------------------------------------
// Per (b,h): chunked two-level prefix/suffix sums over sorted keys.
//   U1[i] = sum_{j>=i} e^{a_j} Vp[idx_j]   (suffix),  S1 scalar analog
//   U2[i] = sum_{j< i} e^{0.2 a_j} Vp[idx_j] (prefix), S2 scalar analog
// block = 1024 threads = 16 chunks x 64 d
// ---------------------------------------------------------------------------
__global__ __launch_bounds__(1024) void prefix_kernel(
    const float* __restrict__ sortedA, const int* __restrict__ sortedIdx,
    const float* __restrict__ Vp, float* __restrict__ U1,
    float* __restrict__ U2, float* __restrict__ S1, float* __restrict__ S2) {
  int bh = blockIdx.x, b = bh >> 3, h = bh & 7;
  __shared__ float E1[1024], E2[1024];
  __shared__ int IDX[1024];
  __shared__ float tot1[16][64], tot2[16][64];
  __shared__ float off1R[16][64], off2[16][64];
  __shared__ float stot1[16], stot2[16], soff1R[16], soff2[16];
  int t = threadIdx.x;
  {
    float a = sortedA[bh * 1024 + t];
    E1[t] = __expf(a);
    E2[t] = __expf(NS * a);
    IDX[t] = sortedIdx[bh * 1024 + t];
  }
  __syncthreads();
  int c = t >> 6, d = t & 63;
  const float* vbase = Vp + (size_t)b * 1024 * 512 + h * 64 + d;
  // phase 1: chunk totals
  float t1 = 0.f, t2 = 0.f, s1 = 0.f, s2 = 0.f;
#pragma unroll 4
  for (int j = 0; j < 64; j++) {
    int i = c * 64 + j;
    float v = vbase[(size_t)IDX[i] * 512];
    float e1 = E1[i], e2 = E2[i];
    t1 += e1 * v; t2 += e2 * v; s1 += e1; s2 += e2;
  }
  tot1[c][d] = t1; tot2[c][d] = t2;
  if (d == 0) { stot1[c] = s1; stot2[c] = s2; }
  __syncthreads();
  // phase 2: scan over chunks
  if (t < 64) {
    float sfx = 0.f, pfx = 0.f;
    for (int cc = 15; cc >= 0; cc--) { off1R[cc][t] = sfx; sfx += tot1[cc][t]; }
    for (int cc = 0; cc < 16; cc++) { off2[cc][t] = pfx; pfx += tot2[cc][t]; }
  }
  if (t == 64) {
    float sfx = 0.f;
    for (int cc = 15; cc >= 0; cc--) { soff1R[cc] = sfx; sfx += stot1[cc]; }
  }
  if (t == 65) {
    float pfx = 0.f;
    for (int cc = 0; cc < 16; cc++) { soff2[cc] = pfx; pfx += stot2[cc]; }
  }
  __syncthreads();
  // phase 3: emit prefixes
  float acc1 = 0.f;
  float acc2 = off2[c][d];
  float sacc1 = 0.f, sacc2 = soff2[c];
  float o1r = off1R[c][d], tt1 = tot1[c][d];
  float so1r = soff1R[c], st1 = stot1[c];
  float* u1base = U1 + (size_t)bh * 1025 * 64 + d;
  float* u2base = U2 + (size_t)bh * 1025 * 64 + d;
#pragma unroll 4
  for (int j = 0; j < 64; j++) {
    int i = c * 64 + j;
    float v = vbase[(size_t)IDX[i] * 512];
    float e1 = E1[i], e2 = E2[i];
    u1base[(size_t)i * 64] = o1r + (tt1 - acc1);
    acc1 += e1 * v;
    acc2 += e2 * v;
    u2base[(size_t)(i + 1) * 64] = acc2;
    if (d == 0) S1[bh * 1025 + i] = so1r + (st1 - sacc1);
    sacc1 += e1;
    sacc2 += e2;
    if (d == 0) S2[bh * 1025 + i + 1] = sacc2;
  }
  if (t < 64) {
    u1base[(size_t)1024 * 64] = 0.f;  // c==0 so d==t
    u2base[0] = 0.f;
  }
  if (t == 0) { S1[bh * 1025 + 1024] = 0.f; S2[bh * 1025] = 0.f; }
}

// ---------------------------------------------------------------------------
// out[b,q,h*64+d] = (e^x U1[ix] + e^{0.2x} U2[ix]) / (e^x S1 + e^{0.2x} S2)
//                   + bias[h,d]
// one wave per (b,q,h) task
// ---------------------------------------------------------------------------
__global__ __launch_bounds__(256) void final_kernel(
    const float* __restrict__ aQ, const int* __restrict__ ixArr,
    const float* __restrict__ U1, const float* __restrict__ U2,
    const float* __restrict__ S1, const float* __restrict__ S2,
    const float* __restrict__ bias, float* __restrict__ out) {
  int t = threadIdx.x;
  int w = t >> 6, d = t & 63;
  int task = blockIdx.x * 4 + w;  // b*8192 + q*8 + h
  int h = task & 7, b = task >> 13;
  int q = (task >> 3) & 1023;
  int bh = b * 8 + h;
  int ix = ixArr[task];
  float x = aQ[task];
  float ex = __expf(x), e2x = __expf(NS * x);
  const float* u1 = U1 + ((size_t)bh * 1025 + ix) * 64;
  const float* u2 = U2 + ((size_t)bh * 1025 + ix) * 64;
  float Z = ex * S1[bh * 1025 + ix] + e2x * S2[bh * 1025 + ix];
  float val = (ex * u1[d] + e2x * u2[d]) / Z + bias[h * 64 + d];
  out[((size_t)(b * 1024 + q)) * 512 + h * 64 + d] = val;
}

// ---------------------------------------------------------------------------
// Fallback (small ws): direct attention via the same exp-split, LDS-tiled Vp
// block per (b,h,qtile of 64); 4 waves x 16 queries each
// ---------------------------------------------------------------------------
__global__ __launch_bounds__(256) void direct_kernel(
    const float* __restrict__ aQ, const float* __restrict__ aK,
    const float* __restrict__ Vp, const float* __restrict__ bias,
    float* __restrict__ out) {
  int id = blockIdx.x;
  int qt = id & 15, h = (id >> 4) & 7, b = id >> 7;
  __shared__ float AK[1024], E1s[1024], E2s[1024];
  __shared__ __align__(16) float VT[128][64];
  __shared__ float XQ[64];
  int t = threadIdx.x;
  for (int i = t; i < 1024; i += 256) {
    float a = aK[(size_t)(b * 1024 + i) * 8 + h];
    AK[i] = a; E1s[i] = __expf(a); E2s[i] = __expf(NS * a);
  }
  if (t < 64) XQ[t] = aQ[(size_t)(b * 1024 + qt * 64 + t) * 8 + h];
  __syncthreads();
  int w = t >> 6, d = t & 63;
  float xq[16], ex[16], e2x[16], acc[16], z[16];
#pragma unroll
  for (int qi = 0; qi < 16; qi++) {
    float x = XQ[w * 16 + qi];
    xq[qi] = x; ex[qi] = __expf(x); e2x[qi] = __expf(NS * x);
    acc[qi] = 0.f; z[qi] = 0.f;
  }
  for (int kt = 0; kt < 8; kt++) {
    __syncthreads();
    for (int i = t; i < 128 * 64; i += 256) {
      VT[i >> 6][i & 63] =
          Vp[(size_t)(b * 1024 + kt * 128 + (i >> 6)) * 512 + h * 64 + (i & 63)];
    }
    __syncthreads();
    for (int kk = 0; kk < 128; kk++) {
      int k = kt * 128 + kk;
      float a = AK[k], e1 = E1s[k], e2 = E2s[k];
      float v = VT[kk][d];
#pragma unroll
      for (int qi = 0; qi < 16; qi++) {
        float wsel = (a + xq[qi] > 0.f) ? (ex[qi] * e1) : (e2x[qi] * e2);
        acc[qi] += wsel * v;
        z[qi] += wsel;
      }
    }
  }
#pragma unroll
  for (int qi = 0; qi < 16; qi++) {
    int q = qt * 64 + w * 16 + qi;
    out[(size_t)(b * 1024 + q) * 512 + h * 64 + d] =
        acc[qi] / z[qi] + bias[h * 64 + d];
  }
}

// ---------------------------------------------------------------------------
extern "C" void kernel_launch(void* const* d_in, const int* in_sizes, int n_in,
                              void* d_out, int out_size, void* d_ws,
                              size_t ws_size, hipStream_t stream) {
  const float* Q = (const float*)d_in[0];
  const float* K = (const float*)d_in[1];
  const float* V = (const float*)d_in[2];
  const float* WQ = (const float*)d_in[3];
  const float* WK = (const float*)d_in[4];
  const float* WV = (const float*)d_in[5];
  const float* bias = (const float*)d_in[6];
  float* out = (float*)d_out;
  char* ws = (char*)d_ws;

  const size_t oAQ = 0;
  const size_t oAK = 262144;
  const size_t oSA = 524288;
  const size_t oSI = 786432;
  const size_t oIX = 1048576;
  const size_t oS1 = 1310720;
  const size_t oS2 = 1573120;
  const size_t oU1 = 2097152;
  const size_t oU2 = oU1 + 16793600;
  const size_t NEED_MAIN = oU2 + 16793600;  // ~34 MB
  const size_t NEED_FB = 524288 + 16777216; // ~17 MB

  if (ws_size >= NEED_MAIN) {
    float* aQ = (float*)(ws + oAQ);
    float* aK = (float*)(ws + oAK);
    float* sA = (float*)(ws + oSA);
    int* sI = (int*)(ws + oSI);
    int* ixA = (int*)(ws + oIX);
    float* S1 = (float*)(ws + oS1);
    float* S2 = (float*)(ws + oS2);
    float* U1 = (float*)(ws + oU1);
    float* U2 = (float*)(ws + oU2);
    float* Vp = out;  // d_out as GEMM scratch; final_kernel fully overwrites it
    hipLaunchKernelGGL(proj8_kernel, dim3(2048), dim3(256), 0, stream, Q, WQ, aQ);
    hipLaunchKernelGGL(proj8_kernel, dim3(2048), dim3(256), 0, stream, K, WK, aK);
    hipLaunchKernelGGL(sort_kernel, dim3(64), dim3(1024), 0, stream, aK, sA, sI);
    hipLaunchKernelGGL(ix_kernel, dim3(256), dim3(256), 0, stream, aQ, sA, ixA);
    hipLaunchKernelGGL(vproj_gemm, dim3(128, 8), dim3(256), 0, stream, V, WV, Vp);
    hipLaunchKernelGGL(prefix_kernel, dim3(64), dim3(1024), 0, stream, sA, sI,
                       Vp, U1, U2, S1, S2);
    hipLaunchKernelGGL(final_kernel, dim3(16384), dim3(256), 0, stream, aQ, ixA,
                       U1, U2, S1, S2, bias, out);
  } else if (ws_size >= NEED_FB) {
    float* aQ = (float*)(ws + 0);
    float* aK = (float*)(ws + 262144);
    float* Vp = (float*)(ws + 524288);
    hipLaunchKernelGGL(proj8_kernel, dim3(2048), dim3(256), 0, stream, Q, WQ, aQ);
    hipLaunchKernelGGL(proj8_kernel, dim3(2048), dim3(256), 0, stream, K, WK, aK);
    hipLaunchKernelGGL(vproj_gemm, dim3(128, 8), dim3(256), 0, stream, V, WV, Vp);
    hipLaunchKernelGGL(direct_kernel, dim3(1024), dim3(256), 0, stream, aQ, aK,
                       Vp, bias, out);
  }
  // if ws_size < NEED_FB: nothing we can do without allocations; bench will
  // fail and tell us the actual workspace budget.
}

// Round 2
// 96.432 us; speedup vs baseline: 1.5261x; 1.5261x over previous
//
#include <hip/hip_runtime.h>
#include <hip/hip_bf16.h>

#define NS 0.2f

// Problem sizes (fixed): B=8, S=1024, D=512, H=8, OD=64

typedef _Float16 half8 __attribute__((ext_vector_type(8)));
typedef float f32x4 __attribute__((ext_vector_type(4)));

// ---------------------------------------------------------------------------
// aX[row*8+h] = sum_d X[row][d] * W[h][d]     (rows = B*S = 8192)
// block = 256 (4 waves), each wave computes one row's 8 head-dots
// ---------------------------------------------------------------------------
__global__ __launch_bounds__(256) void proj8_kernel(
    const float* __restrict__ X, const float* __restrict__ W,
    float* __restrict__ aX) {
  __shared__ __align__(16) float Wl[8 * 512];
  int t = threadIdx.x;
#pragma unroll
  for (int i = 0; i < 16; i++) Wl[i * 256 + t] = W[i * 256 + t];
  __syncthreads();
  int w = t >> 6, lane = t & 63;
  int row = blockIdx.x * 4 + w;
  const float* x = X + (size_t)row * 512;
  float4 x0 = *(const float4*)(x + lane * 4);
  float4 x1 = *(const float4*)(x + 256 + lane * 4);
  float acc[8];
#pragma unroll
  for (int h = 0; h < 8; h++) {
    const float* wl = Wl + h * 512;
    float4 w0 = *(const float4*)(wl + lane * 4);
    float4 w1 = *(const float4*)(wl + 256 + lane * 4);
    float a = x0.x * w0.x + x0.y * w0.y + x0.z * w0.z + x0.w * w0.w +
              x1.x * w1.x + x1.y * w1.y + x1.z * w1.z + x1.w * w1.w;
#pragma unroll
    for (int off = 32; off > 0; off >>= 1) a += __shfl_xor(a, off);
    acc[h] = a;
  }
  if (lane == 0) {
    float* o = aX + (size_t)row * 8;
    o[0] = acc[0]; o[1] = acc[1]; o[2] = acc[2]; o[3] = acc[3];
    o[4] = acc[4]; o[5] = acc[5]; o[6] = acc[6]; o[7] = acc[7];
  }
}

// ---------------------------------------------------------------------------
// Vproj = V(8192x512) @ WV.T(512x512) -> C(8192x512)
// f16 MFMA (f32 accumulate). Tile 64x64, BK=32, 4 waves (2x2 quadrants),
// each wave 32x32 via 2x2 mfma_f32_16x16x32_f16 fragments.
// Reg-staged f32->f16 conversion into XOR-swizzled LDS:
//   elem (r,k) stored at r*32 + ((k>>3) ^ ((r>>1)&3))*8 + (k&7)
// -> ds_read_b128 fragment reads are 2-way max (free).
// ---------------------------------------------------------------------------
__global__ __launch_bounds__(256) void vproj_mfma(
    const float* __restrict__ A, const float* __restrict__ Wv,
    float* __restrict__ C) {
  __shared__ __align__(16) _Float16 As[64 * 32];
  __shared__ __align__(16) _Float16 Bs[64 * 32];
  int t = threadIdx.x;
  int m0 = blockIdx.x * 64, n0 = blockIdx.y * 64;
  int lane = t & 63, wid = t >> 6;
  int wr = wid >> 1, wc = wid & 1;
  // staging: thread t handles row sr, k-chunk sc (8 consecutive f32)
  int sr = t >> 2, sc = t & 3;
  const float* ap = A + (size_t)(m0 + sr) * 512 + sc * 8;
  const float* bp = Wv + (size_t)(n0 + sr) * 512 + sc * 8;
  _Float16* aw = As + sr * 32 + (sc ^ ((sr >> 1) & 3)) * 8;
  _Float16* bw = Bs + sr * 32 + (sc ^ ((sr >> 1) & 3)) * 8;
  int fr = lane & 15, fs = lane >> 4;
  f32x4 acc[2][2];
#pragma unroll
  for (int i = 0; i < 2; i++)
#pragma unroll
    for (int j = 0; j < 2; j++)
#pragma unroll
      for (int r = 0; r < 4; r++) acc[i][j][r] = 0.f;

  for (int k0 = 0; k0 < 512; k0 += 32) {
    float4 av0 = *(const float4*)(ap + k0);
    float4 av1 = *(const float4*)(ap + k0 + 4);
    float4 bv0 = *(const float4*)(bp + k0);
    float4 bv1 = *(const float4*)(bp + k0 + 4);
    __syncthreads();  // previous iteration's fragment reads done
    half8 ah, bh;
    ah[0] = (_Float16)av0.x; ah[1] = (_Float16)av0.y;
    ah[2] = (_Float16)av0.z; ah[3] = (_Float16)av0.w;
    ah[4] = (_Float16)av1.x; ah[5] = (_Float16)av1.y;
    ah[6] = (_Float16)av1.z; ah[7] = (_Float16)av1.w;
    bh[0] = (_Float16)bv0.x; bh[1] = (_Float16)bv0.y;
    bh[2] = (_Float16)bv0.z; bh[3] = (_Float16)bv0.w;
    bh[4] = (_Float16)bv1.x; bh[5] = (_Float16)bv1.y;
    bh[6] = (_Float16)bv1.z; bh[7] = (_Float16)bv1.w;
    *(half8*)aw = ah;
    *(half8*)bw = bh;
    __syncthreads();
    half8 af[2], bf[2];
#pragma unroll
    for (int i = 0; i < 2; i++) {
      int R = wr * 32 + i * 16 + fr;
      af[i] = *(half8*)(As + R * 32 + ((fs ^ ((R >> 1) & 3)) * 8));
    }
#pragma unroll
    for (int j = 0; j < 2; j++) {
      int Cc = wc * 32 + j * 16 + fr;
      bf[j] = *(half8*)(Bs + Cc * 32 + ((fs ^ ((Cc >> 1) & 3)) * 8));
    }
#pragma unroll
    for (int i = 0; i < 2; i++)
#pragma unroll
      for (int j = 0; j < 2; j++)
        acc[i][j] = __builtin_amdgcn_mfma_f32_16x16x32_f16(af[i], bf[j],
                                                           acc[i][j], 0, 0, 0);
  }
  // C/D layout (m89-verified): col = lane&15, row = (lane>>4)*4 + reg
#pragma unroll
  for (int i = 0; i < 2; i++)
#pragma unroll
    for (int j = 0; j < 2; j++) {
      int row = m0 + wr * 32 + i * 16 + fs * 4;
      int col = n0 + wc * 32 + j * 16 + fr;
#pragma unroll
      for (int r = 0; r < 4; r++)
        C[(size_t)(row + r) * 512 + col] = acc[i][j][r];
    }
}

// ---------------------------------------------------------------------------
// f32 LDS-tiled GEMM (fallback path only)
// ---------------------------------------------------------------------------
__global__ __launch_bounds__(256) void vproj_gemm(
    const float* __restrict__ A, const float* __restrict__ Wv,
    float* __restrict__ C) {
  __shared__ __align__(16) float As[16][68];
  __shared__ __align__(16) float Bs[16][68];
  int t = threadIdx.x;
  int m0 = blockIdx.x * 64, n0 = blockIdx.y * 64;
  int tx = t & 15, ty = t >> 4;
  int lr = t >> 2, lk = (t & 3) * 4;
  float acc[4][4] = {{0.f}};
  const float* ap = A + (size_t)(m0 + lr) * 512 + lk;
  const float* bp = Wv + (size_t)(n0 + lr) * 512 + lk;
  for (int k0 = 0; k0 < 512; k0 += 16) {
    float4 av = *(const float4*)(ap + k0);
    float4 bv = *(const float4*)(bp + k0);
    __syncthreads();
    As[lk + 0][lr] = av.x; As[lk + 1][lr] = av.y;
    As[lk + 2][lr] = av.z; As[lk + 3][lr] = av.w;
    Bs[lk + 0][lr] = bv.x; Bs[lk + 1][lr] = bv.y;
    Bs[lk + 2][lr] = bv.z; Bs[lk + 3][lr] = bv.w;
    __syncthreads();
#pragma unroll
    for (int kk = 0; kk < 16; kk++) {
      float4 a4 = *(const float4*)&As[kk][ty * 4];
      float4 b4 = *(const float4*)&Bs[kk][tx * 4];
      float aa[4] = {a4.x, a4.y, a4.z, a4.w};
      float bb[4] = {b4.x, b4.y, b4.z, b4.w};
#pragma unroll
      for (int i = 0; i < 4; i++)
#pragma unroll
        for (int j = 0; j < 4; j++) acc[i][j] += aa[i] * bb[j];
    }
  }
#pragma unroll
  for (int i = 0; i < 4; i++) {
    float4 o = {acc[i][0], acc[i][1], acc[i][2], acc[i][3]};
    *(float4*)(C + (size_t)(m0 + ty * 4 + i) * 512 + n0 + tx * 4) = o;
  }
}

// ---------------------------------------------------------------------------
// Per (b,h): bitonic sort of aK column (1024 values) ascending, with index
// ---------------------------------------------------------------------------
__global__ __launch_bounds__(1024) void sort_kernel(
    const float* __restrict__ aK, float* __restrict__ sortedA,
    int* __restrict__ sortedIdx) {
  int bh = blockIdx.x, b = bh >> 3, h = bh & 7;
  __shared__ float key[1024];
  __shared__ int idx[1024];
  int t = threadIdx.x;
  key[t] = aK[(size_t)(b * 1024 + t) * 8 + h];
  idx[t] = t;
  __syncthreads();
  for (int len = 2; len <= 1024; len <<= 1) {
    for (int stride = len >> 1; stride > 0; stride >>= 1) {
      int p = t ^ stride;
      if (p > t) {
        bool up = ((t & len) == 0);
        float k1 = key[t], k2 = key[p];
        if ((k1 > k2) == up) {
          int i1 = idx[t];
          key[t] = k2; key[p] = k1;
          idx[t] = idx[p]; idx[p] = i1;
        }
      }
      __syncthreads();
    }
  }
  sortedA[bh * 1024 + t] = key[t];
  sortedIdx[bh * 1024 + t] = idx[t];
}

// ---------------------------------------------------------------------------
// ix[task] = lower bound: first index in sortedA[bh] with a > -x
// task = b*8192 + q*8 + h
// ---------------------------------------------------------------------------
__global__ __launch_bounds__(256) void ix_kernel(
    const float* __restrict__ aQ, const float* __restrict__ sortedA,
    int* __restrict__ ixArr) {
  int t = blockIdx.x * 256 + threadIdx.x;  // 0..65535
  int h = t & 7, b = t >> 13;
  int bh = b * 8 + h;
  float negx = -aQ[t];
  const float* a = sortedA + bh * 1024;
  int lo = 0, hi = 1024;
  while (lo < hi) {
    int mid = (lo + hi) >> 1;
    if (a[mid] <= negx) lo = mid + 1; else hi = mid;
  }
  ixArr[t] = lo;
}

// ---------------------------------------------------------------------------
// Per (b,h): chunked two-level prefix/suffix sums over sorted keys.
//   U1[i] = sum_{j>=i} e^{a_j} Vp[idx_j]   (suffix),  S1 scalar analog
//   U2[i] = sum_{j< i} e^{0.2 a_j} Vp[idx_j] (prefix), S2 scalar analog
// block = 1024 threads = 16 chunks x 64 d
// ---------------------------------------------------------------------------
__global__ __launch_bounds__(1024) void prefix_kernel(
    const float* __restrict__ sortedA, const int* __restrict__ sortedIdx,
    const float* __restrict__ Vp, float* __restrict__ U1,
    float* __restrict__ U2, float* __restrict__ S1, float* __restrict__ S2) {
  int bh = blockIdx.x, b = bh >> 3, h = bh & 7;
  __shared__ float E1[1024], E2[1024];
  __shared__ int IDX[1024];
  __shared__ float tot1[16][64], tot2[16][64];
  __shared__ float off1R[16][64], off2[16][64];
  __shared__ float stot1[16], stot2[16], soff1R[16], soff2[16];
  int t = threadIdx.x;
  {
    float a = sortedA[bh * 1024 + t];
    E1[t] = __expf(a);
    E2[t] = __expf(NS * a);
    IDX[t] = sortedIdx[bh * 1024 + t];
  }
  __syncthreads();
  int c = t >> 6, d = t & 63;
  const float* vbase = Vp + (size_t)b * 1024 * 512 + h * 64 + d;
  // phase 1: chunk totals
  float t1 = 0.f, t2 = 0.f, s1 = 0.f, s2 = 0.f;
#pragma unroll 4
  for (int j = 0; j < 64; j++) {
    int i = c * 64 + j;
    float v = vbase[(size_t)IDX[i] * 512];
    float e1 = E1[i], e2 = E2[i];
    t1 += e1 * v; t2 += e2 * v; s1 += e1; s2 += e2;
  }
  tot1[c][d] = t1; tot2[c][d] = t2;
  if (d == 0) { stot1[c] = s1; stot2[c] = s2; }
  __syncthreads();
  // phase 2: scan over chunks
  if (t < 64) {
    float sfx = 0.f, pfx = 0.f;
    for (int cc = 15; cc >= 0; cc--) { off1R[cc][t] = sfx; sfx += tot1[cc][t]; }
    for (int cc = 0; cc < 16; cc++) { off2[cc][t] = pfx; pfx += tot2[cc][t]; }
  }
  if (t == 64) {
    float sfx = 0.f;
    for (int cc = 15; cc >= 0; cc--) { soff1R[cc] = sfx; sfx += stot1[cc]; }
  }
  if (t == 65) {
    float pfx = 0.f;
    for (int cc = 0; cc < 16; cc++) { soff2[cc] = pfx; pfx += stot2[cc]; }
  }
  __syncthreads();
  // phase 3: emit prefixes
  float acc1 = 0.f;
  float acc2 = off2[c][d];
  float sacc1 = 0.f, sacc2 = soff2[c];
  float o1r = off1R[c][d], tt1 = tot1[c][d];
  float so1r = soff1R[c], st1 = stot1[c];
  float* u1base = U1 + (size_t)bh * 1025 * 64 + d;
  float* u2base = U2 + (size_t)bh * 1025 * 64 + d;
#pragma unroll 4
  for (int j = 0; j < 64; j++) {
    int i = c * 64 + j;
    float v = vbase[(size_t)IDX[i] * 512];
    float e1 = E1[i], e2 = E2[i];
    u1base[(size_t)i * 64] = o1r + (tt1 - acc1);
    acc1 += e1 * v;
    acc2 += e2 * v;
    u2base[(size_t)(i + 1) * 64] = acc2;
    if (d == 0) S1[bh * 1025 + i] = so1r + (st1 - sacc1);
    sacc1 += e1;
    sacc2 += e2;
    if (d == 0) S2[bh * 1025 + i + 1] = sacc2;
  }
  if (t < 64) {
    u1base[(size_t)1024 * 64] = 0.f;  // c==0 so d==t
    u2base[0] = 0.f;
  }
  if (t == 0) { S1[bh * 1025 + 1024] = 0.f; S2[bh * 1025] = 0.f; }
}

// ---------------------------------------------------------------------------
// out[b,q,h*64+d] = (e^x U1[ix] + e^{0.2x} U2[ix]) / (e^x S1 + e^{0.2x} S2)
//                   + bias[h,d]
// one wave per (b,q,h) task
// ---------------------------------------------------------------------------
__global__ __launch_bounds__(256) void final_kernel(
    const float* __restrict__ aQ, const int* __restrict__ ixArr,
    const float* __restrict__ U1, const float* __restrict__ U2,
    const float* __restrict__ S1, const float* __restrict__ S2,
    const float* __restrict__ bias, float* __restrict__ out) {
  int t = threadIdx.x;
  int w = t >> 6, d = t & 63;
  int task = blockIdx.x * 4 + w;  // b*8192 + q*8 + h
  int h = task & 7, b = task >> 13;
  int q = (task >> 3) & 1023;
  int bh = b * 8 + h;
  int ix = ixArr[task];
  float x = aQ[task];
  float ex = __expf(x), e2x = __expf(NS * x);
  const float* u1 = U1 + ((size_t)bh * 1025 + ix) * 64;
  const float* u2 = U2 + ((size_t)bh * 1025 + ix) * 64;
  float Z = ex * S1[bh * 1025 + ix] + e2x * S2[bh * 1025 + ix];
  float val = (ex * u1[d] + e2x * u2[d]) / Z + bias[h * 64 + d];
  out[((size_t)(b * 1024 + q)) * 512 + h * 64 + d] = val;
}

// ---------------------------------------------------------------------------
// Fallback (small ws): direct attention via the same exp-split, LDS-tiled Vp
// ---------------------------------------------------------------------------
__global__ __launch_bounds__(256) void direct_kernel(
    const float* __restrict__ aQ, const float* __restrict__ aK,
    const float* __restrict__ Vp, const float* __restrict__ bias,
    float* __restrict__ out) {
  int id = blockIdx.x;
  int qt = id & 15, h = (id >> 4) & 7, b = id >> 7;
  __shared__ float AK[1024], E1s[1024], E2s[1024];
  __shared__ __align__(16) float VT[128][64];
  __shared__ float XQ[64];
  int t = threadIdx.x;
  for (int i = t; i < 1024; i += 256) {
    float a = aK[(size_t)(b * 1024 + i) * 8 + h];
    AK[i] = a; E1s[i] = __expf(a); E2s[i] = __expf(NS * a);
  }
  if (t < 64) XQ[t] = aQ[(size_t)(b * 1024 + qt * 64 + t) * 8 + h];
  __syncthreads();
  int w = t >> 6, d = t & 63;
  float xq[16], ex[16], e2x[16], acc[16], z[16];
#pragma unroll
  for (int qi = 0; qi < 16; qi++) {
    float x = XQ[w * 16 + qi];
    xq[qi] = x; ex[qi] = __expf(x); e2x[qi] = __expf(NS * x);
    acc[qi] = 0.f; z[qi] = 0.f;
  }
  for (int kt = 0; kt < 8; kt++) {
    __syncthreads();
    for (int i = t; i < 128 * 64; i += 256) {
      VT[i >> 6][i & 63] =
          Vp[(size_t)(b * 1024 + kt * 128 + (i >> 6)) * 512 + h * 64 + (i & 63)];
    }
    __syncthreads();
    for (int kk = 0; kk < 128; kk++) {
      int k = kt * 128 + kk;
      float a = AK[k], e1 = E1s[k], e2 = E2s[k];
      float v = VT[kk][d];
#pragma unroll
      for (int qi = 0; qi < 16; qi++) {
        float wsel = (a + xq[qi] > 0.f) ? (ex[qi] * e1) : (e2x[qi] * e2);
        acc[qi] += wsel * v;
        z[qi] += wsel;
      }
    }
  }
#pragma unroll
  for (int qi = 0; qi < 16; qi++) {
    int q = qt * 64 + w * 16 + qi;
    out[(size_t)(b * 1024 + q) * 512 + h * 64 + d] =
        acc[qi] / z[qi] + bias[h * 64 + d];
  }
}

// ---------------------------------------------------------------------------
extern "C" void kernel_launch(void* const* d_in, const int* in_sizes, int n_in,
                              void* d_out, int out_size, void* d_ws,
                              size_t ws_size, hipStream_t stream) {
  const float* Q = (const float*)d_in[0];
  const float* K = (const float*)d_in[1];
  const float* V = (const float*)d_in[2];
  const float* WQ = (const float*)d_in[3];
  const float* WK = (const float*)d_in[4];
  const float* WV = (const float*)d_in[5];
  const float* bias = (const float*)d_in[6];
  float* out = (float*)d_out;
  char* ws = (char*)d_ws;

  const size_t oAQ = 0;
  const size_t oAK = 262144;
  const size_t oSA = 524288;
  const size_t oSI = 786432;
  const size_t oIX = 1048576;
  const size_t oS1 = 1310720;
  const size_t oS2 = 1573120;
  const size_t oU1 = 2097152;
  const size_t oU2 = oU1 + 16793600;
  const size_t NEED_MAIN = oU2 + 16793600;  // ~34 MB
  const size_t NEED_FB = 524288 + 16777216; // ~17 MB

  if (ws_size >= NEED_MAIN) {
    float* aQ = (float*)(ws + oAQ);
    float* aK = (float*)(ws + oAK);
    float* sA = (float*)(ws + oSA);
    int* sI = (int*)(ws + oSI);
    int* ixA = (int*)(ws + oIX);
    float* S1 = (float*)(ws + oS1);
    float* S2 = (float*)(ws + oS2);
    float* U1 = (float*)(ws + oU1);
    float* U2 = (float*)(ws + oU2);
    float* Vp = out;  // d_out as GEMM scratch; final_kernel fully overwrites it
    hipLaunchKernelGGL(proj8_kernel, dim3(2048), dim3(256), 0, stream, Q, WQ, aQ);
    hipLaunchKernelGGL(proj8_kernel, dim3(2048), dim3(256), 0, stream, K, WK, aK);
    hipLaunchKernelGGL(sort_kernel, dim3(64), dim3(1024), 0, stream, aK, sA, sI);
    hipLaunchKernelGGL(ix_kernel, dim3(256), dim3(256), 0, stream, aQ, sA, ixA);
    hipLaunchKernelGGL(vproj_mfma, dim3(128, 8), dim3(256), 0, stream, V, WV, Vp);
    hipLaunchKernelGGL(prefix_kernel, dim3(64), dim3(1024), 0, stream, sA, sI,
                       Vp, U1, U2, S1, S2);
    hipLaunchKernelGGL(final_kernel, dim3(16384), dim3(256), 0, stream, aQ, ixA,
                       U1, U2, S1, S2, bias, out);
  } else if (ws_size >= NEED_FB) {
    float* aQ = (float*)(ws + 0);
    float* aK = (float*)(ws + 262144);
    float* Vp = (float*)(ws + 524288);
    hipLaunchKernelGGL(proj8_kernel, dim3(2048), dim3(256), 0, stream, Q, WQ, aQ);
    hipLaunchKernelGGL(proj8_kernel, dim3(2048), dim3(256), 0, stream, K, WK, aK);
    hipLaunchKernelGGL(vproj_gemm, dim3(128, 8), dim3(256), 0, stream, V, WV, Vp);
    hipLaunchKernelGGL(direct_kernel, dim3(1024), dim3(256), 0, stream, aQ, aK,
                       Vp, bias, out);
  }
}